// Round 2
// baseline (1581.942 us; speedup 1.0000x reference)
//
#include <hip/hip_runtime.h>

typedef unsigned int uint32;
typedef unsigned short ushort16;
typedef __attribute__((ext_vector_type(8))) short short8;
typedef __attribute__((ext_vector_type(4))) float floatx4;

#define MFMA16(a, b, c) __builtin_amdgcn_mfma_f32_16x16x32_bf16((a), (b), (c), 0, 0, 0)

__device__ __forceinline__ float lo2f(uint32 u) { return __uint_as_float(u << 16); }
__device__ __forceinline__ float hi2f(uint32 u) { return __uint_as_float(u & 0xffff0000u); }
__device__ __forceinline__ float us2f(ushort16 u) { return __uint_as_float(((uint32)u) << 16); }
__device__ __forceinline__ ushort16 f2us(float f) {
    uint32 u = __float_as_uint(f);
    return (ushort16)((u + 0x7fffu + ((u >> 16) & 1u)) >> 16);
}
__device__ __forceinline__ uint32 pack2(float a, float b) {
    return (uint32)f2us(a) | ((uint32)f2us(b) << 16);
}

// ---------- convert the 5 weight matrices (fp32 -> bf16) into ws ----------
__global__ __launch_bounds__(256) void cvt_weights(const float* __restrict__ Wq,
                                                   const float* __restrict__ Wk,
                                                   const float* __restrict__ Wv,
                                                   const float* __restrict__ Wo,
                                                   const float* __restrict__ Wl,
                                                   ushort16* __restrict__ dst) {
    size_t idx = ((size_t)blockIdx.x * 256 + threadIdx.x) * 8;  // < 5*262144
    int w = (int)(idx >> 18);
    const float* src;
    switch (w) {
        case 0: src = Wq; break;
        case 1: src = Wk; break;
        case 2: src = Wv; break;
        case 3: src = Wo; break;
        default: src = Wl; break;
    }
    size_t off = idx & 262143;
    const float4* s4 = (const float4*)(src + off);
    float4 a = s4[0], c = s4[1];
    *(uint4*)(dst + idx) = make_uint4(pack2(a.x, a.y), pack2(a.z, a.w),
                                      pack2(c.x, c.y), pack2(c.z, c.w));
}

// ---------------- LayerNorm rows of 512: fp32 in -> bf16 out ----------------
__global__ __launch_bounds__(256) void ln_rows(const float* __restrict__ x,
                                               ushort16* __restrict__ y,
                                               const float* __restrict__ g,
                                               const float* __restrict__ b) {
    int row = blockIdx.x * 4 + (threadIdx.x >> 6);
    int lane = threadIdx.x & 63;
    const float4* xr = (const float4*)(x + (size_t)row * 512);
    float4 u0 = xr[2 * lane], u1 = xr[2 * lane + 1];
    float f[8] = { u0.x, u0.y, u0.z, u0.w, u1.x, u1.y, u1.z, u1.w };
    float s = 0.f, q = 0.f;
#pragma unroll
    for (int i = 0; i < 8; i++) { s += f[i]; q += f[i] * f[i]; }
#pragma unroll
    for (int m = 1; m < 64; m <<= 1) { s += __shfl_xor(s, m); q += __shfl_xor(q, m); }
    float mean = s * (1.f / 512.f);
    float var = q * (1.f / 512.f) - mean * mean;
    float rstd = rsqrtf(var + 1e-5f);
    const float4* gr = (const float4*)g;
    const float4* br = (const float4*)b;
    float4 g0 = gr[2 * lane], g1 = gr[2 * lane + 1];
    float4 b0 = br[2 * lane], b1 = br[2 * lane + 1];
    float gf[8] = { g0.x, g0.y, g0.z, g0.w, g1.x, g1.y, g1.z, g1.w };
    float bf_[8] = { b0.x, b0.y, b0.z, b0.w, b1.x, b1.y, b1.z, b1.w };
    uint32 o[4];
#pragma unroll
    for (int i = 0; i < 4; i++) {
        float r0 = (f[2 * i] - mean) * rstd * gf[2 * i] + bf_[2 * i];
        float r1 = (f[2 * i + 1] - mean) * rstd * gf[2 * i + 1] + bf_[2 * i + 1];
        o[i] = pack2(r0, r1);
    }
    ((uint4*)(y + (size_t)row * 512))[lane] = make_uint4(o[0], o[1], o[2], o[3]);
}

// ------- C[M,512] = A[M,512] @ W[512,512]^T + bias (bf16 A/W, fp32 bias) -------
__global__ __launch_bounds__(256) void gemm_bt(const ushort16* __restrict__ A,
                                               const ushort16* __restrict__ W,
                                               const float* __restrict__ bias,
                                               ushort16* __restrict__ C) {
    int wave = threadIdx.x >> 6, lane = threadIdx.x & 63;
    int quad = lane >> 4, l16 = lane & 15;
    int m0 = (blockIdx.x >> 3) * 64 + wave * 16;
    int n0 = (blockIdx.x & 7) * 64;
    floatx4 acc[4];
#pragma unroll
    for (int nt = 0; nt < 4; nt++) {
        float bb = bias[n0 + nt * 16 + l16];
        acc[nt] = (floatx4){bb, bb, bb, bb};
    }
    const ushort16* arow = A + (size_t)(m0 + l16) * 512 + quad * 8;
#pragma unroll 2
    for (int kb = 0; kb < 512; kb += 32) {
        short8 a = *(const short8*)(arow + kb);
#pragma unroll
        for (int nt = 0; nt < 4; nt++) {
            short8 b = *(const short8*)(W + (size_t)(n0 + nt * 16 + l16) * 512 + kb + quad * 8);
            acc[nt] = MFMA16(a, b, acc[nt]);
        }
    }
#pragma unroll
    for (int nt = 0; nt < 4; nt++)
#pragma unroll
        for (int j = 0; j < 4; j++)
            C[(size_t)(m0 + quad * 4 + j) * 512 + n0 + nt * 16 + l16] = f2us(acc[nt][j]);
}

// ---------------- fused attention + 2 GEMMs + 2 LayerNorms ----------------
// One block = one video v, one 32-row t-tile. 512 threads = 8 waves; wave w owns
// output cols [w*64, w*64+64). attn tile in LDS with XOR-8-chunk swizzle.
__global__ __launch_bounds__(512, 2) void fused_attn(
    const ushort16* __restrict__ qbuf, const ushort16* __restrict__ kbuf,
    const ushort16* __restrict__ vbuf,
    const ushort16* __restrict__ Wo, const float* __restrict__ bo,
    const ushort16* __restrict__ Wl, const float* __restrict__ bl,
    const float* __restrict__ g2, const float* __restrict__ b2,
    const float* __restrict__ g3, const float* __restrict__ b3,
    float* __restrict__ out) {
    __shared__ __align__(16) ushort16 attn_s[32 * 512];  // 32 KB, swizzled
    __shared__ __align__(16) ushort16 k_s[12 * 512];     // 12 KB
    __shared__ __align__(16) ushort16 v_s[12 * 512];     // 12 KB
    __shared__ float red_s[8][32];
    __shared__ float red_q[8][32];
    __shared__ float mean_s[32];
    __shared__ float rstd_s[32];

    int tid = threadIdx.x;
    int wave = tid >> 6, lane = tid & 63;
    int quad = lane >> 4, l16 = lane & 15;
    int vno = blockIdx.x >> 4;
    int t0 = (blockIdx.x & 15) << 5;

    // ---- load K/V rows for this video (12x512 each, bf16) ----
    {
        const uint4* ks = (const uint4*)(kbuf + (size_t)vno * 12 * 512);
        const uint4* vs = (const uint4*)(vbuf + (size_t)vno * 12 * 512);
        for (int i = tid; i < 768; i += 512) {
            ((uint4*)k_s)[i] = ks[i];
            ((uint4*)v_s)[i] = vs[i];
        }
    }
    __syncthreads();

    // ---- stage 1: scores over F=12, softmax, weighted combine -> attn tile ----
    {
        int pair = tid >> 1, dhalf = tid & 1;
        int t = pair & 31, h = pair >> 5;
        int colw = (h * 64 + dhalf * 32) >> 1;  // word offset in a 256-word row
        const uint32* qp = (const uint32*)(qbuf + (size_t)(t0 + t) * 512) + colw;
        uint32 qw[16];
#pragma unroll
        for (int i = 0; i < 4; i++) {
            uint4 tmp = ((const uint4*)qp)[i];
            qw[4 * i] = tmp.x; qw[4 * i + 1] = tmp.y; qw[4 * i + 2] = tmp.z; qw[4 * i + 3] = tmp.w;
        }
        float s[12];
#pragma unroll
        for (int f = 0; f < 12; f++) s[f] = 0.f;
        const uint32* kw = (const uint32*)k_s + colw;
#pragma unroll
        for (int w = 0; w < 16; w++) {
            float qx = lo2f(qw[w]), qy = hi2f(qw[w]);
#pragma unroll
            for (int f = 0; f < 12; f++) {
                uint32 kk = kw[f * 256 + w];
                s[f] += qx * lo2f(kk) + qy * hi2f(kk);
            }
        }
        float mx = -1e30f;
#pragma unroll
        for (int f = 0; f < 12; f++) {
            s[f] += __shfl_xor(s[f], 1);  // combine the two halves of the dot
            s[f] *= 0.125f;               // 1/sqrt(64)
            mx = fmaxf(mx, s[f]);
        }
        float sum = 0.f;
#pragma unroll
        for (int f = 0; f < 12; f++) {
            s[f] = exp2f((s[f] - mx) * 1.44269504f);
            sum += s[f];
        }
        float inv = 1.f / sum;
#pragma unroll
        for (int f = 0; f < 12; f++) s[f] *= inv;
        const uint32* vw = (const uint32*)v_s + colw;
        uint32* aw = (uint32*)attn_s;
        int trow = t * 256;
#pragma unroll
        for (int w = 0; w < 16; w++) {
            float ax = 0.f, ay = 0.f;
#pragma unroll
            for (int f = 0; f < 12; f++) {
                uint32 vv = vw[f * 256 + w];
                ax += s[f] * lo2f(vv);
                ay += s[f] * hi2f(vv);
            }
            int c = h * 64 + dhalf * 32 + 2 * w;  // element col
            int chunk = c >> 3;
            aw[trow + (((chunk ^ (t & 7)) << 2) | ((c & 7) >> 1))] = pack2(ax, ay);
        }
    }
    __syncthreads();

    int nb = wave << 6;
    floatx4 acc[2][4];

    // ---- GEMM1: o = attn @ Wo^T + bo ----
#pragma unroll
    for (int nt = 0; nt < 4; nt++) {
        float bb = bo[nb + nt * 16 + l16];
        acc[0][nt] = (floatx4){bb, bb, bb, bb};
        acc[1][nt] = acc[0][nt];
    }
    {
        const ushort16* a0 = attn_s + (size_t)l16 * 512;
        const ushort16* a1 = attn_s + (size_t)(16 + l16) * 512;
        int sw = l16 & 7;
#pragma unroll 2
        for (int kb = 0; kb < 512; kb += 32) {
            int ch = (kb >> 3) + quad;
            short8 af0 = *(const short8*)(a0 + ((ch ^ sw) << 3));
            short8 af1 = *(const short8*)(a1 + ((ch ^ sw) << 3));
#pragma unroll
            for (int nt = 0; nt < 4; nt++) {
                short8 b = *(const short8*)(Wo + (size_t)(nb + nt * 16 + l16) * 512 + kb + quad * 8);
                acc[0][nt] = MFMA16(af0, b, acc[0][nt]);
                acc[1][nt] = MFMA16(af1, b, acc[1][nt]);
            }
        }
    }

    // ---- LN2: attn_out = LN(o) -> back into attn_s (bf16) ----
#pragma unroll
    for (int mt = 0; mt < 2; mt++)
#pragma unroll
        for (int j = 0; j < 4; j++) {
            float sv = 0.f, sq = 0.f;
#pragma unroll
            for (int nt = 0; nt < 4; nt++) { float x = acc[mt][nt][j]; sv += x; sq += x * x; }
#pragma unroll
            for (int m = 1; m < 16; m <<= 1) { sv += __shfl_xor(sv, m); sq += __shfl_xor(sq, m); }
            if (l16 == 0) { int r = mt * 16 + quad * 4 + j; red_s[wave][r] = sv; red_q[wave][r] = sq; }
        }
    __syncthreads();
    if (tid < 32) {
        float sv = 0.f, sq = 0.f;
#pragma unroll
        for (int w = 0; w < 8; w++) { sv += red_s[w][tid]; sq += red_q[w][tid]; }
        float mean = sv * (1.f / 512.f);
        float var = sq * (1.f / 512.f) - mean * mean;
        mean_s[tid] = mean;
        rstd_s[tid] = rsqrtf(var + 1e-5f);
    }
    __syncthreads();
    {
        float gf[4], bf_[4];
#pragma unroll
        for (int nt = 0; nt < 4; nt++) {
            gf[nt] = g2[nb + nt * 16 + l16];
            bf_[nt] = b2[nb + nt * 16 + l16];
        }
#pragma unroll
        for (int mt = 0; mt < 2; mt++)
#pragma unroll
            for (int j = 0; j < 4; j++) {
                int r = mt * 16 + quad * 4 + j;
                float mn = mean_s[r], rs = rstd_s[r];
#pragma unroll
                for (int nt = 0; nt < 4; nt++) {
                    int n = nb + nt * 16 + l16;
                    float val = (acc[mt][nt][j] - mn) * rs * gf[nt] + bf_[nt];
                    attn_s[r * 512 + (((n >> 3) ^ (r & 7)) << 3) + (n & 7)] = f2us(val);
                }
            }
    }
    __syncthreads();

    // ---- GEMM2: linear = attn_out @ Wl^T + bl ----
#pragma unroll
    for (int nt = 0; nt < 4; nt++) {
        float bb = bl[nb + nt * 16 + l16];
        acc[0][nt] = (floatx4){bb, bb, bb, bb};
        acc[1][nt] = acc[0][nt];
    }
    {
        const ushort16* a0 = attn_s + (size_t)l16 * 512;
        const ushort16* a1 = attn_s + (size_t)(16 + l16) * 512;
        int sw = l16 & 7;
#pragma unroll 2
        for (int kb = 0; kb < 512; kb += 32) {
            int ch = (kb >> 3) + quad;
            short8 af0 = *(const short8*)(a0 + ((ch ^ sw) << 3));
            short8 af1 = *(const short8*)(a1 + ((ch ^ sw) << 3));
#pragma unroll
            for (int nt = 0; nt < 4; nt++) {
                short8 b = *(const short8*)(Wl + (size_t)(nb + nt * 16 + l16) * 512 + kb + quad * 8);
                acc[0][nt] = MFMA16(af0, b, acc[0][nt]);
                acc[1][nt] = MFMA16(af1, b, acc[1][nt]);
            }
        }
    }

    // ---- residual: sum = attn_out + linear ----
#pragma unroll
    for (int mt = 0; mt < 2; mt++)
#pragma unroll
        for (int j = 0; j < 4; j++) {
            int r = mt * 16 + quad * 4 + j;
#pragma unroll
            for (int nt = 0; nt < 4; nt++) {
                int n = nb + nt * 16 + l16;
                acc[mt][nt][j] += us2f(attn_s[r * 512 + (((n >> 3) ^ (r & 7)) << 3) + (n & 7)]);
            }
        }

    // ---- LN3 reduction ----
#pragma unroll
    for (int mt = 0; mt < 2; mt++)
#pragma unroll
        for (int j = 0; j < 4; j++) {
            float sv = 0.f, sq = 0.f;
#pragma unroll
            for (int nt = 0; nt < 4; nt++) { float x = acc[mt][nt][j]; sv += x; sq += x * x; }
#pragma unroll
            for (int m = 1; m < 16; m <<= 1) { sv += __shfl_xor(sv, m); sq += __shfl_xor(sq, m); }
            if (l16 == 0) { int r = mt * 16 + quad * 4 + j; red_s[wave][r] = sv; red_q[wave][r] = sq; }
        }
    __syncthreads();
    if (tid < 32) {
        float sv = 0.f, sq = 0.f;
#pragma unroll
        for (int w = 0; w < 8; w++) { sv += red_s[w][tid]; sq += red_q[w][tid]; }
        float mean = sv * (1.f / 512.f);
        float var = sq * (1.f / 512.f) - mean * mean;
        mean_s[tid] = mean;
        rstd_s[tid] = rsqrtf(var + 1e-5f);
    }
    __syncthreads();

    // ---- LN3 normalize + fp32 store straight from registers ----
    {
        float gf[4], bf_[4];
#pragma unroll
        for (int nt = 0; nt < 4; nt++) {
            gf[nt] = g3[nb + nt * 16 + l16];
            bf_[nt] = b3[nb + nt * 16 + l16];
        }
        float* outb = out + (size_t)(vno * 512 + t0) * 512;
#pragma unroll
        for (int mt = 0; mt < 2; mt++)
#pragma unroll
            for (int j = 0; j < 4; j++) {
                int r = mt * 16 + quad * 4 + j;
                float mn = mean_s[r], rs = rstd_s[r];
#pragma unroll
                for (int nt = 0; nt < 4; nt++) {
                    int n = nb + nt * 16 + l16;
                    outb[(size_t)r * 512 + n] = (acc[mt][nt][j] - mn) * rs * gf[nt] + bf_[nt];
                }
            }
    }
}

extern "C" void kernel_launch(void* const* d_in, const int* in_sizes, int n_in,
                              void* d_out, int out_size, void* d_ws, size_t ws_size,
                              hipStream_t stream) {
    const float* text = (const float*)d_in[0];
    const float* video = (const float*)d_in[1];
    const float* Wq = (const float*)d_in[2];
    const float* bq = (const float*)d_in[3];
    const float* Wk = (const float*)d_in[4];
    const float* bk = (const float*)d_in[5];
    const float* Wv = (const float*)d_in[6];
    const float* bv = (const float*)d_in[7];
    const float* Wo = (const float*)d_in[8];
    const float* bo = (const float*)d_in[9];
    const float* Wl = (const float*)d_in[10];
    const float* bl = (const float*)d_in[11];
    const float* g1 = (const float*)d_in[12];
    const float* b1 = (const float*)d_in[13];
    const float* g2 = (const float*)d_in[14];
    const float* b2 = (const float*)d_in[15];
    const float* g3 = (const float*)d_in[16];
    const float* b3 = (const float*)d_in[17];

    ushort16* ws = (ushort16*)d_ws;
    ushort16* Wb = ws;                        // 5 * 262144 bf16 weights
    ushort16* Wq_b = Wb + 0 * 262144;
    ushort16* Wk_b = Wb + 1 * 262144;
    ushort16* Wv_b = Wb + 2 * 262144;
    ushort16* Wo_b = Wb + 3 * 262144;
    ushort16* Wl_b = Wb + 4 * 262144;
    ushort16* t_ln = Wb + 5 * 262144;         // 512*512
    ushort16* vid_ln = t_ln + 262144;         // 6144*512
    ushort16* qb = vid_ln + 3145728;          // 512*512
    ushort16* kb_ = qb + 262144;              // 6144*512
    ushort16* vb_ = kb_ + 3145728;            // 6144*512   (~22.5 MB total)
    float* outp = (float*)d_out;

    cvt_weights<<<640, 256, 0, stream>>>(Wq, Wk, Wv, Wo, Wl, Wb);
    ln_rows<<<128, 256, 0, stream>>>(text, t_ln, g1, b1);
    ln_rows<<<1536, 256, 0, stream>>>(video, vid_ln, g1, b1);
    gemm_bt<<<64, 256, 0, stream>>>(t_ln, Wq_b, bq, qb);
    gemm_bt<<<768, 256, 0, stream>>>(vid_ln, Wk_b, bk, kb_);
    gemm_bt<<<768, 256, 0, stream>>>(vid_ln, Wv_b, bv, vb_);
    fused_attn<<<8192, 512, 0, stream>>>(qb, kb_, vb_, Wo_b, bo, Wl_b, bl,
                                         g2, b2, g3, b3, outp);
}